// Round 6
// baseline (216.863 us; speedup 1.0000x reference)
//
#include <hip/hip_runtime.h>
#include <math.h>

// B=64, A=64, MULS=((64,0),(32,1),(16,2)) -> DIM_IN=240, NB=32, H=128, MOUT=112
#define H_ 128
#define NB_ 32

#define INV_STEP 3.1f
#define HALF_PI 1.57079632679489662f
#define INV_SQRT_NB 0.17677669529663689f
#define INV_SQRT_H 0.08838834764831845f
#define NORM0 0.125f
#define NORM1 0.10206207261596575f
#define NORM2 0.11180339887498948f
#define S3 1.7320508075688772f
#define S5 2.23606797749979f
#define S15 3.872983346207417f
#define LN2 0.6931471805599453f

typedef __attribute__((ext_vector_type(8))) _Float16 half8;
typedef __attribute__((ext_vector_type(4))) float f32x4;

__device__ __forceinline__ float ssp_f(float x) {
    float t = 5.0f * x;
    float s = fmaxf(t, 0.0f) + __logf(1.0f + __expf(-fabsf(t)));
    return (s - LN2) * 0.2f;
}
__device__ __forceinline__ float sp_f(float x) {
    float t = 5.0f * x;
    float s = fmaxf(t, 0.0f) + __logf(1.0f + __expf(-fabsf(t)));
    return s * 0.2f;
}

// ---------------------------------------------------------------------------
// w2half: W2 (fp32 row-major) -> fp16 MFMA-B-fragment order in ws.
// pos = ((kt*8+nt)*64 + lane)*8 + j ; k = kt*32+(lane>>4)*8+j ; n = nt*16+(lane&15)
// Also zeroes the per-z completion counters (graph replays re-run this first,
// so the fused-finalize counters are reset every iteration).
// ---------------------------------------------------------------------------
__global__ void w2half(const float* __restrict__ W2, _Float16* __restrict__ w2f,
                       int* __restrict__ counters) {
    if (blockIdx.x == 0 && threadIdx.x < 64) counters[threadIdx.x] = 0;
    const int e0 = (blockIdx.x * 256 + threadIdx.x) * 4;
    #pragma unroll
    for (int t = 0; t < 4; ++t) {
        const int pos = e0 + t;
        const int j = pos & 7, lane = (pos >> 3) & 63, fn = pos >> 9;
        const int kt = fn >> 3, nt = fn & 7;
        const int k = kt * 32 + (lane >> 4) * 8 + j;
        const int n = nt * 16 + (lane & 15);
        w2f[pos] = (_Float16)W2[k * 128 + n];
    }
}

// ---------------------------------------------------------------------------
// pair4: one block per (z, 4-b-group). Round-6 = round-5 with the fused
// finalize race fixed:
//   R5 FAILED (absmax 2.5e-2 / 468 first-run): tid==0's atomicAdd signal was
//   issued with NO __syncthreads after the partial stores -> wave 0 signaled
//   "done" before waves 1-3 stored rows 16-63; the last block read them
//   stale (poisoned workspace). Fix = canonical last-block-done sequence:
//   store -> threadfence -> SYNCTHREADS -> atomicAdd -> syncthreads ->
//   threadfence -> read.
// Carried from R5 (perf-wise unfalsified):
//   - __launch_bounds__(256,4): arch cap 64 (unified/2 rule: (256,2)->128,
//     (256,3)->84, (256,4)->64); R4 body needs 60 -> fits. LDS 40960 x4 =
//     exactly 160 KiB -> 4 blocks/CU, 16 waves/CU.
//   - W1 staged in LDS (16 KB) with 16B-slot XOR swizzle: element e of row k
//     at float4-slot k*32 + kt*8 + (e^(k&7)); read applies the same XOR.
// ---------------------------------------------------------------------------
__global__ __launch_bounds__(256, 4)
void pair4(const float* __restrict__ rep, const float* __restrict__ geom,
           const float* __restrict__ W1, const float* __restrict__ W3,
           const _Float16* __restrict__ w2f, const float* __restrict__ mask,
           float* __restrict__ partial, int* __restrict__ counters,
           float* __restrict__ out) {
    const int bg = blockIdx.x;           // b in [4bg, 4bg+4)
    const int z  = blockIdx.y;
    const int tid = threadIdx.x;
    const int wv = tid >> 6, lane = tid & 63;
    const int m = lane & 15, quad = lane >> 4;

    __shared__ __align__(16) _Float16 sVf[8192];       // 16384 B  [b<4][kt][lane][j]
    __shared__ __align__(16) float sW1[4096];          // 16384 B  swizzled [32][128]
    __shared__ __align__(16) _Float16 sH2t[4][16][40]; // 5120 B   per-wave [a][h2local+pad]
    __shared__ float sYw[4][16][8];                    // 2048 B
    __shared__ float sPosA[192];                       // 768 B
    __shared__ float sPosB[12];                        // 48 B
    __shared__ int lastFlag;                           // 4 B
    // total ~40756 B -> 40960 rounded -> 4 blocks/CU exactly (160 KiB)

    // ---- startup: stage geom ----
    if (tid < 192) sPosA[tid] = geom[z * 192 + tid];
    else if (tid < 204) sPosB[tid - 192] = geom[((size_t)z * 64 + bg * 4) * 3 + (tid - 192)];

    // ---- startup: stage W1 into LDS, 16B-slot swizzled ----
    {
        const float4* srcW1 = reinterpret_cast<const float4*>(W1);
        float4* dstW1 = reinterpret_cast<float4*>(sW1);
        #pragma unroll
        for (int i = 0; i < 4; ++i) {
            const int p = tid + i * 256;         // 0..1023 float4 slots
            const int k = p >> 5, s = p & 31;
            const int sw = (s & 24) | ((s ^ k) & 7);
            dstW1[k * 32 + sw] = srcW1[p];
        }
    }

    // ---- V compute: 512 slots (b<4, h<128); emit fp16 B-frags ----
    // rep rows read from global: wave-uniform address -> broadcast, L1/L2-hit.
    #pragma unroll
    for (int i = 0; i < 2; ++i) {
        const int s = tid + i * 256;
        const int b = s >> 7, h = s & 127;
        const float* w3r = W3 + (size_t)h * 112;
        const float* rr = rep + ((size_t)z * 64 + bg * 4 + b) * 240;
        float a0 = 0.f, a1 = 0.f, a2 = 0.f, a3 = 0.f, a4 = 0.f,
              a5 = 0.f, a6 = 0.f, a7 = 0.f, a8 = 0.f;
        #pragma unroll 4
        for (int m4 = 0; m4 < 16; ++m4) {            // l=0
            float4 w = *reinterpret_cast<const float4*>(w3r + m4 * 4);
            const float* wp = reinterpret_cast<const float*>(&w);
            #pragma unroll
            for (int c = 0; c < 4; ++c) a0 = fmaf(wp[c], rr[m4 * 4 + c], a0);
        }
        #pragma unroll 2
        for (int u4 = 0; u4 < 8; ++u4) {             // l=1
            float4 w = *reinterpret_cast<const float4*>(w3r + 64 + u4 * 4);
            const float* wp = reinterpret_cast<const float*>(&w);
            #pragma unroll
            for (int c = 0; c < 4; ++c) {
                int u = u4 * 4 + c;
                a1 = fmaf(wp[c], rr[64 + 3 * u + 0], a1);
                a2 = fmaf(wp[c], rr[64 + 3 * u + 1], a2);
                a3 = fmaf(wp[c], rr[64 + 3 * u + 2], a3);
            }
        }
        #pragma unroll 2
        for (int u4 = 0; u4 < 4; ++u4) {             // l=2
            float4 w = *reinterpret_cast<const float4*>(w3r + 96 + u4 * 4);
            const float* wp = reinterpret_cast<const float*>(&w);
            #pragma unroll
            for (int c = 0; c < 4; ++c) {
                int u = u4 * 4 + c;
                a4 = fmaf(wp[c], rr[160 + 5 * u + 0], a4);
                a5 = fmaf(wp[c], rr[160 + 5 * u + 1], a5);
                a6 = fmaf(wp[c], rr[160 + 5 * u + 2], a6);
                a7 = fmaf(wp[c], rr[160 + 5 * u + 3], a7);
                a8 = fmaf(wp[c], rr[160 + 5 * u + 4], a8);
            }
        }
        const float n0 = NORM0 * INV_SQRT_H, n1 = NORM1 * INV_SQRT_H, n2 = NORM2 * INV_SQRT_H;
        float vals[9];
        vals[0] = a0 * n0;
        vals[1] = a1 * n1; vals[2] = a2 * n1; vals[3] = a3 * n1;
        vals[4] = a4 * n2; vals[5] = a5 * n2; vals[6] = a6 * n2;
        vals[7] = a7 * n2; vals[8] = a8 * n2;
        // h = kt*32 + qd*8 + j ; frag pos = (b*4+kt)*512 + (qd*16+n)*8 + j
        const int kt = h >> 5, qd = (h >> 3) & 3, j = h & 7;
        _Float16* base = sVf + (b * 4 + kt) * 512 + qd * 128 + j;
        #pragma unroll
        for (int n = 0; n < 16; ++n)
            base[n * 8] = (n < 9) ? (_Float16)vals[n] : (_Float16)0.0f;
    }
    __syncthreads();   // sVf + sW1 + sPos* ready

    // ---- main loop: one b per iteration, NOT unrolled (register budget) ----
    const int aLoc = wv * 16 + m;
    const float ax = sPosA[aLoc * 3 + 0];
    const float ay = sPosA[aLoc * 3 + 1];
    const float az = sPosA[aLoc * 3 + 2];
    float outAcc[4] = {0.f, 0.f, 0.f, 0.f};

    #pragma unroll 1
    for (int bl = 0; bl < 4; ++bl) {
        const float bx = sPosB[bl * 3 + 0];
        const float by = sPosB[bl * 3 + 1];
        const float bz = sPosB[bl * 3 + 2];
        const float dx = ax - bx, dy = ay - by, dz = az - bz;
        const float r2 = dx * dx + dy * dy + dz * dz;

        // radial basis coefficients + swizzled LDS W1 row offsets
        const float r = sqrtf(fmaxf(r2, 1e-12f));
        const float u = r * INV_STEP;
        int i0 = (int)floorf(u);
        const float d0 = u - (float)i0;
        float c0 = (i0 >= 0 && i0 < NB_) ? __cosf(HALF_PI * d0) : 0.f;
        const int i1 = i0 + 1;
        const float d1 = d0 - 1.0f;
        float c1 = (i1 >= 0 && i1 < NB_ && d1 > -1.0f) ? __cosf(HALF_PI * d1) : 0.f;
        const int i0c = min(max(i0, 0), NB_ - 1);
        const int i1c = min(max(i1, 0), NB_ - 1);
        const float* r0 = sW1 + i0c * 128;
        const float* r1 = sW1 + i1c * 128;
        const int x0 = i0c & 7, x1 = i1c & 7;
        const float c0v = c0 * INV_SQRT_NB;
        const float c1v = c1 * INV_SQRT_NB;

        // Y for this b (quad==0 lanes own a-row m); wave-private, no barrier
        if (quad == 0) {
            const float nzf = (r2 > 1e-10f) ? 1.0f : 0.0f;
            const float ir = rsqrtf(fmaxf(r2, 1e-12f));
            const float x = dx * ir, y = dy * ir, zz = dz * ir;
            float4 g0, g1;
            g0.x = S3 * x * nzf; g0.y = S3 * y * nzf; g0.z = S3 * zz * nzf;
            g0.w = S15 * x * y * nzf;
            g1.x = S15 * y * zz * nzf;
            g1.y = 0.5f * S5 * (3.0f * zz * zz - 1.0f) * nzf;
            g1.z = S15 * x * zz * nzf;
            g1.w = 0.5f * S15 * (x * x - y * y) * nzf;
            *reinterpret_cast<float4*>(&sYw[wv][m][0]) = g0;
            *reinterpret_cast<float4*>(&sYw[wv][m][4]) = g1;
        }

        f32x4 acc[8];
        #pragma unroll
        for (int nt = 0; nt < 8; ++nt) {
            acc[nt][0] = 0.f; acc[nt][1] = 0.f;
            acc[nt][2] = 0.f; acc[nt][3] = 0.f;
        }

        // ---- layer1 (fp16 A-frag regs, W1 from swizzled LDS) + layer2 MFMA ----
        #pragma unroll 2
        for (int kt = 0; kt < 4; ++kt) {
            const int sb = kt * 8;          // 8 float4-slots per kt window
            const int e0 = quad * 2;
            float4 wa0 = *reinterpret_cast<const float4*>(r0 + (sb + ((e0 ^ x0) & 7)) * 4);
            float4 wa1 = *reinterpret_cast<const float4*>(r0 + (sb + (((e0 + 1) ^ x0) & 7)) * 4);
            float4 wb0 = *reinterpret_cast<const float4*>(r1 + (sb + ((e0 ^ x1) & 7)) * 4);
            float4 wb1 = *reinterpret_cast<const float4*>(r1 + (sb + (((e0 + 1) ^ x1) & 7)) * 4);
            const float* a0p = reinterpret_cast<const float*>(&wa0);
            const float* a1p = reinterpret_cast<const float*>(&wa1);
            const float* b0p = reinterpret_cast<const float*>(&wb0);
            const float* b1p = reinterpret_cast<const float*>(&wb1);
            half8 ah;
            #pragma unroll
            for (int j = 0; j < 8; ++j) {
                float w0 = (j < 4) ? a0p[j] : a1p[j - 4];
                float w1v = (j < 4) ? b0p[j] : b1p[j - 4];
                ah[j] = (_Float16)ssp_f(fmaf(c0v, w0, c1v * w1v));
            }
            const _Float16* bhp = w2f + (size_t)(kt * 8) * 512 + (size_t)lane * 8;
            #pragma unroll
            for (int nt = 0; nt < 8; ++nt) {
                half8 bh = *reinterpret_cast<const half8*>(bhp + nt * 512);
                acc[nt] = __builtin_amdgcn_mfma_f32_16x16x32_f16(ah, bh, acc[nt], 0, 0, 0);
            }
        }

        // ---- epilogue: ssp + per-kt fp16 transpose, combine vs V frags ----
        f32x4 T0 = {0.f, 0.f, 0.f, 0.f};
        f32x4 T1 = {0.f, 0.f, 0.f, 0.f};
        #pragma unroll
        for (int kt = 0; kt < 4; ++kt) {
            #pragma unroll
            for (int ntl = 0; ntl < 2; ++ntl)
                #pragma unroll
                for (int reg = 0; reg < 4; ++reg)
                    sH2t[wv][quad * 4 + reg][ntl * 16 + m] =
                        (_Float16)ssp_f(acc[kt * 2 + ntl][reg] * INV_SQRT_H);
            half8 ah2 = *reinterpret_cast<const half8*>(&sH2t[wv][m][quad * 8]);
            half8 bv = *reinterpret_cast<const half8*>(sVf + (bl * 4 + kt) * 512 + lane * 8);
            if (kt & 1) T1 = __builtin_amdgcn_mfma_f32_16x16x32_f16(ah2, bv, T1, 0, 0, 0);
            else        T0 = __builtin_amdgcn_mfma_f32_16x16x32_f16(ah2, bv, T0, 0, 0, 0);
        }

        // G-weight (T C-layout: col=lane&15=cm, row=quad*4+reg=a-local)
        const int comp = (m >= 1 && m <= 8) ? (m - 1) : 0;
        float ps[4];
        #pragma unroll
        for (int reg = 0; reg < 4; ++reg) {
            const int row = quad * 4 + reg;
            const float Tv = T0[reg] + T1[reg];
            const float yv = sYw[wv][row][comp];
            const float g = (m == 0) ? 1.0f : ((m <= 8) ? yv : 0.0f);
            ps[reg] = Tv * g;
        }
        #pragma unroll
        for (int off = 1; off < 16; off <<= 1)
            #pragma unroll
            for (int reg = 0; reg < 4; ++reg)
                ps[reg] += __shfl_xor(ps[reg], off);
        #pragma unroll
        for (int reg = 0; reg < 4; ++reg) outAcc[reg] += ps[reg];
    }

    // ---- write partial[z][bg][a]: lanes m==0 hold a = wv*16 + quad*4 + reg ----
    if (m == 0) {
        float4 st;
        st.x = outAcc[0]; st.y = outAcc[1]; st.z = outAcc[2]; st.w = outAcc[3];
        *reinterpret_cast<float4*>(partial + ((size_t)(z * 16 + bg)) * 64 + wv * 16 + quad * 4) = st;
    }

    // ---- fused finalize: canonical last-block-done sequence ----
    __threadfence();      // release: each thread's partial stores visible
    __syncthreads();      // ALL waves' stores + fences complete before signal
    if (tid == 0)
        lastFlag = (atomicAdd(&counters[z], 1) == 15);
    __syncthreads();
    if (lastFlag) {
        __threadfence();  // acquire: other blocks' partials
        if (tid < 64) {
            const int a = tid;
            const float mk = mask[z * 64 + a];
            float s = mk;
            #pragma unroll
            for (int off = 32; off > 0; off >>= 1) s += __shfl_xor(s, off);
            const float inv = rsqrtf(s);
            float acc2 = 0.f;
            #pragma unroll
            for (int bg2 = 0; bg2 < 16; ++bg2)
                acc2 += partial[((size_t)(z * 16 + bg2)) * 64 + a];
            out[z * 64 + a] = sp_f(acc2 * inv) * mk;
        }
    }
}

extern "C" void kernel_launch(void* const* d_in, const int* in_sizes, int n_in,
                              void* d_out, int out_size, void* d_ws, size_t ws_size,
                              hipStream_t stream) {
    const float* rep  = (const float*)d_in[0];
    const float* geom = (const float*)d_in[1];
    const float* mask = (const float*)d_in[2];
    const float* W1   = (const float*)d_in[3];
    const float* W2   = (const float*)d_in[4];
    const float* W3   = (const float*)d_in[5];
    float* out = (float*)d_out;

    _Float16* w2f = (_Float16*)d_ws;                          // 32768 B
    float* partial = (float*)((char*)d_ws + 32768);           // 64*16*64*4 = 262144 B
    int* counters = (int*)((char*)d_ws + 32768 + 262144);     // 256 B

    w2half<<<16, 256, 0, stream>>>(W2, w2f, counters);
    pair4<<<dim3(16, 64), 256, 0, stream>>>(rep, geom, W1, W3, w2f, mask,
                                            partial, counters, out);
}

// Round 7
// 207.494 us; speedup vs baseline: 1.0452x; 1.0452x over previous
//
#include <hip/hip_runtime.h>
#include <math.h>

// B=64, A=64, MULS=((64,0),(32,1),(16,2)) -> DIM_IN=240, NB=32, H=128, MOUT=112
#define H_ 128
#define NB_ 32

#define INV_STEP 3.1f
#define HALF_PI 1.57079632679489662f
#define INV_SQRT_NB 0.17677669529663689f
#define INV_SQRT_H 0.08838834764831845f
#define NORM0 0.125f
#define NORM1 0.10206207261596575f
#define NORM2 0.11180339887498948f
#define S3 1.7320508075688772f
#define S5 2.23606797749979f
#define S15 3.872983346207417f
#define LN2 0.6931471805599453f

typedef __attribute__((ext_vector_type(8))) _Float16 half8;
typedef __attribute__((ext_vector_type(4))) float f32x4;

__device__ __forceinline__ float ssp_f(float x) {
    float t = 5.0f * x;
    float s = fmaxf(t, 0.0f) + __logf(1.0f + __expf(-fabsf(t)));
    return (s - LN2) * 0.2f;
}
__device__ __forceinline__ float sp_f(float x) {
    float t = 5.0f * x;
    float s = fmaxf(t, 0.0f) + __logf(1.0f + __expf(-fabsf(t)));
    return s * 0.2f;
}

// ---------------------------------------------------------------------------
// w2half: W2 (fp32 row-major) -> fp16 MFMA-B-fragment order in ws.
// pos = ((kt*8+nt)*64 + lane)*8 + j ; k = kt*32+(lane>>4)*8+j ; n = nt*16+(lane&15)
// Also zeroes the per-z completion counters (graph replays re-run this first).
// ---------------------------------------------------------------------------
__global__ void w2half(const float* __restrict__ W2, _Float16* __restrict__ w2f,
                       int* __restrict__ counters) {
    if (blockIdx.x == 0 && threadIdx.x < 64) counters[threadIdx.x] = 0;
    const int e0 = (blockIdx.x * 256 + threadIdx.x) * 4;
    #pragma unroll
    for (int t = 0; t < 4; ++t) {
        const int pos = e0 + t;
        const int j = pos & 7, lane = (pos >> 3) & 63, fn = pos >> 9;
        const int kt = fn >> 3, nt = fn & 7;
        const int k = kt * 32 + (lane >> 4) * 8 + j;
        const int n = nt * 16 + (lane & 15);
        w2f[pos] = (_Float16)W2[k * 128 + n];
    }
}

// ---------------------------------------------------------------------------
// pair4: one block per (z, 4-b-group). Round-7:
// Ledger over R0-R6: VALU issue time is invariant (~47-50 µs); duration is
// set by latency hiding, and REGISTER-FUNDED ILP beats occupancy here
// (R0: 128 regs/2-b ILP/occ19 -> 82us; R4: 60 regs/no ILP/occ36 -> 98us;
// R6: 52 regs/no ILP -> 170us). So:
//   - __launch_bounds__(256,2): 128 arch regs (R0-proven: VGPR=128, 0 spill,
//     VALUBusy 56%) with R0's exact 2-b-pair main loop (2 passes x 2 b).
//   - grid 1024 (16 bg x 64 z): smaller blocks -> less tail skew than R0.
//   - W1 read from global (R6's LDS-W1 reverted: doubled bank conflicts,
//     and at tight regs its latency was fully exposed anyway).
//   - fp16 per-wave transpose sH2t (R4-verified).
//   - fused finalize, canonical last-block-done sequence (R6-verified).
//   - 16-lane shuffle reduce HOISTED out of the b loop (accumulate unreduced
//     ps into outAcc; reduce once at the end): -3/4 of shuffle/add VALU.
// ---------------------------------------------------------------------------
__global__ __launch_bounds__(256, 2)
void pair4(const float* __restrict__ rep, const float* __restrict__ geom,
           const float* __restrict__ W1, const float* __restrict__ W3,
           const _Float16* __restrict__ w2f, const float* __restrict__ mask,
           float* __restrict__ partial, int* __restrict__ counters,
           float* __restrict__ out) {
    const int bg = blockIdx.x;           // b in [4bg, 4bg+4)
    const int z  = blockIdx.y;
    const int tid = threadIdx.x;
    const int wv = tid >> 6, lane = tid & 63;
    const int m = lane & 15, quad = lane >> 4;

    __shared__ __align__(16) _Float16 sVf[8192];       // 16384 B  [b<4][kt][lane][j]
    __shared__ __align__(16) _Float16 sH2t[4][16][40]; // 5120 B   per-wave [a][h2local+pad]
    __shared__ float sYw[4][2][16][8];                 // 4096 B
    __shared__ float sPosA[192];                       // 768 B
    __shared__ float sPosB[12];                        // 48 B
    __shared__ int lastFlag;                           // 4 B
    // total ~26.4 KB; 2 blocks/CU (reg-bound), LDS irrelevant

    // ---- startup: stage geom ----
    if (tid < 192) sPosA[tid] = geom[z * 192 + tid];
    else if (tid < 204) sPosB[tid - 192] = geom[((size_t)z * 64 + bg * 4) * 3 + (tid - 192)];

    // ---- V compute: 512 slots (b<4, h<128); emit fp16 B-frags ----
    #pragma unroll
    for (int i = 0; i < 2; ++i) {
        const int s = tid + i * 256;
        const int b = s >> 7, h = s & 127;
        const float* w3r = W3 + (size_t)h * 112;
        const float* rr = rep + ((size_t)z * 64 + bg * 4 + b) * 240;
        float a0 = 0.f, a1 = 0.f, a2 = 0.f, a3 = 0.f, a4 = 0.f,
              a5 = 0.f, a6 = 0.f, a7 = 0.f, a8 = 0.f;
        #pragma unroll 4
        for (int m4 = 0; m4 < 16; ++m4) {            // l=0
            float4 w = *reinterpret_cast<const float4*>(w3r + m4 * 4);
            const float* wp = reinterpret_cast<const float*>(&w);
            #pragma unroll
            for (int c = 0; c < 4; ++c) a0 = fmaf(wp[c], rr[m4 * 4 + c], a0);
        }
        #pragma unroll 2
        for (int u4 = 0; u4 < 8; ++u4) {             // l=1
            float4 w = *reinterpret_cast<const float4*>(w3r + 64 + u4 * 4);
            const float* wp = reinterpret_cast<const float*>(&w);
            #pragma unroll
            for (int c = 0; c < 4; ++c) {
                int u = u4 * 4 + c;
                a1 = fmaf(wp[c], rr[64 + 3 * u + 0], a1);
                a2 = fmaf(wp[c], rr[64 + 3 * u + 1], a2);
                a3 = fmaf(wp[c], rr[64 + 3 * u + 2], a3);
            }
        }
        #pragma unroll 2
        for (int u4 = 0; u4 < 4; ++u4) {             // l=2
            float4 w = *reinterpret_cast<const float4*>(w3r + 96 + u4 * 4);
            const float* wp = reinterpret_cast<const float*>(&w);
            #pragma unroll
            for (int c = 0; c < 4; ++c) {
                int u = u4 * 4 + c;
                a4 = fmaf(wp[c], rr[160 + 5 * u + 0], a4);
                a5 = fmaf(wp[c], rr[160 + 5 * u + 1], a5);
                a6 = fmaf(wp[c], rr[160 + 5 * u + 2], a6);
                a7 = fmaf(wp[c], rr[160 + 5 * u + 3], a7);
                a8 = fmaf(wp[c], rr[160 + 5 * u + 4], a8);
            }
        }
        const float n0 = NORM0 * INV_SQRT_H, n1 = NORM1 * INV_SQRT_H, n2 = NORM2 * INV_SQRT_H;
        float vals[9];
        vals[0] = a0 * n0;
        vals[1] = a1 * n1; vals[2] = a2 * n1; vals[3] = a3 * n1;
        vals[4] = a4 * n2; vals[5] = a5 * n2; vals[6] = a6 * n2;
        vals[7] = a7 * n2; vals[8] = a8 * n2;
        // h = kt*32 + qd*8 + j ; frag pos = (b*4+kt)*512 + (qd*16+n)*8 + j
        const int kt = h >> 5, qd = (h >> 3) & 3, j = h & 7;
        _Float16* base = sVf + (b * 4 + kt) * 512 + qd * 128 + j;
        #pragma unroll
        for (int n = 0; n < 16; ++n)
            base[n * 8] = (n < 9) ? (_Float16)vals[n] : (_Float16)0.0f;
    }
    __syncthreads();   // sVf + sPos* ready

    // ---- main loop: 2 passes x 2 b-pairs (R0's proven 128-reg structure) ----
    const int aLoc = wv * 16 + m;
    const float ax = sPosA[aLoc * 3 + 0];
    const float ay = sPosA[aLoc * 3 + 1];
    const float az = sPosA[aLoc * 3 + 2];
    float outAcc[4] = {0.f, 0.f, 0.f, 0.f};

    for (int pass = 0; pass < 2; ++pass) {
        const float* w1p0[2];
        const float* w1p1[2];
        float c0v[2], c1v[2];

        #pragma unroll
        for (int p = 0; p < 2; ++p) {
            const int bl = pass * 2 + p;
            const float bx = sPosB[bl * 3 + 0];
            const float by = sPosB[bl * 3 + 1];
            const float bz = sPosB[bl * 3 + 2];
            const float dx = ax - bx, dy = ay - by, dz = az - bz;
            const float r2 = dx * dx + dy * dy + dz * dz;
            const float r = sqrtf(fmaxf(r2, 1e-12f));
            const float nzf = (r2 > 1e-10f) ? 1.0f : 0.0f;
            const float ir = 1.0f / r;
            const float x = dx * ir, y = dy * ir, zz = dz * ir;
            if (quad == 0) {
                float4 g0, g1;
                g0.x = S3 * x * nzf; g0.y = S3 * y * nzf; g0.z = S3 * zz * nzf;
                g0.w = S15 * x * y * nzf;
                g1.x = S15 * y * zz * nzf;
                g1.y = 0.5f * S5 * (3.0f * zz * zz - 1.0f) * nzf;
                g1.z = S15 * x * zz * nzf;
                g1.w = 0.5f * S15 * (x * x - y * y) * nzf;
                *reinterpret_cast<float4*>(&sYw[wv][p][m][0]) = g0;
                *reinterpret_cast<float4*>(&sYw[wv][p][m][4]) = g1;
            }
            const float u = r * INV_STEP;
            int i0 = (int)floorf(u);
            const float d0 = u - (float)i0;
            float c0 = (i0 >= 0 && i0 < NB_) ? __cosf(HALF_PI * d0) : 0.f;
            const int i1 = i0 + 1;
            const float d1 = d0 - 1.0f;
            float c1 = (i1 >= 0 && i1 < NB_ && d1 > -1.0f) ? __cosf(HALF_PI * d1) : 0.f;
            const int i0c = min(max(i0, 0), NB_ - 1);
            const int i1c = min(max(i1, 0), NB_ - 1);
            w1p0[p] = W1 + i0c * H_;
            w1p1[p] = W1 + i1c * H_;
            c0v[p] = c0 * INV_SQRT_NB;
            c1v[p] = c1 * INV_SQRT_NB;
        }

        f32x4 acc[2][8];
        #pragma unroll
        for (int p = 0; p < 2; ++p)
            #pragma unroll
            for (int nt = 0; nt < 8; ++nt) {
                acc[p][nt][0] = 0.f; acc[p][nt][1] = 0.f;
                acc[p][nt][2] = 0.f; acc[p][nt][3] = 0.f;
            }

        // ---- layer1 (fp16 A-frag regs) + layer2 fp16 MFMA ----
        #pragma unroll
        for (int kt = 0; kt < 4; ++kt) {
            const int koff = kt * 32 + quad * 8;
            half8 ah[2];
            #pragma unroll
            for (int p = 0; p < 2; ++p) {
                float4 wa0 = *reinterpret_cast<const float4*>(w1p0[p] + koff);
                float4 wa1 = *reinterpret_cast<const float4*>(w1p0[p] + koff + 4);
                float4 wb0 = *reinterpret_cast<const float4*>(w1p1[p] + koff);
                float4 wb1 = *reinterpret_cast<const float4*>(w1p1[p] + koff + 4);
                const float* a0p = reinterpret_cast<const float*>(&wa0);
                const float* a1p = reinterpret_cast<const float*>(&wa1);
                const float* b0p = reinterpret_cast<const float*>(&wb0);
                const float* b1p = reinterpret_cast<const float*>(&wb1);
                #pragma unroll
                for (int j = 0; j < 8; ++j) {
                    float w0 = (j < 4) ? a0p[j] : a1p[j - 4];
                    float w1v = (j < 4) ? b0p[j] : b1p[j - 4];
                    ah[p][j] = (_Float16)ssp_f(fmaf(c0v[p], w0, c1v[p] * w1v));
                }
            }
            const _Float16* bhp = w2f + (size_t)(kt * 8) * 512 + (size_t)lane * 8;
            #pragma unroll
            for (int nt = 0; nt < 8; ++nt) {
                half8 bh = *reinterpret_cast<const half8*>(bhp + nt * 512);
                acc[0][nt] = __builtin_amdgcn_mfma_f32_16x16x32_f16(ah[0], bh, acc[0][nt], 0, 0, 0);
                acc[1][nt] = __builtin_amdgcn_mfma_f32_16x16x32_f16(ah[1], bh, acc[1][nt], 0, 0, 0);
            }
        }

        // ---- per-b epilogue ----
        #pragma unroll
        for (int p = 0; p < 2; ++p) {
            const int bl = pass * 2 + p;

            f32x4 T0 = {0.f, 0.f, 0.f, 0.f};
            f32x4 T1 = {0.f, 0.f, 0.f, 0.f};
            #pragma unroll
            for (int kt = 0; kt < 4; ++kt) {
                #pragma unroll
                for (int ntl = 0; ntl < 2; ++ntl)
                    #pragma unroll
                    for (int reg = 0; reg < 4; ++reg)
                        sH2t[wv][quad * 4 + reg][ntl * 16 + m] =
                            (_Float16)ssp_f(acc[p][kt * 2 + ntl][reg] * INV_SQRT_H);
                half8 ah2 = *reinterpret_cast<const half8*>(&sH2t[wv][m][quad * 8]);
                half8 bv = *reinterpret_cast<const half8*>(sVf + (bl * 4 + kt) * 512 + lane * 8);
                if (kt & 1) T1 = __builtin_amdgcn_mfma_f32_16x16x32_f16(ah2, bv, T1, 0, 0, 0);
                else        T0 = __builtin_amdgcn_mfma_f32_16x16x32_f16(ah2, bv, T0, 0, 0, 0);
            }

            // G-weight; reduce DEFERRED: accumulate unreduced lane-partials
            const int comp = (m >= 1 && m <= 8) ? (m - 1) : 0;
            #pragma unroll
            for (int reg = 0; reg < 4; ++reg) {
                const int row = quad * 4 + reg;
                const float Tv = T0[reg] + T1[reg];
                const float yv = sYw[wv][p][row][comp];
                const float g = (m == 0) ? 1.0f : ((m <= 8) ? yv : 0.0f);
                outAcc[reg] = fmaf(Tv, g, outAcc[reg]);
            }
        }
    }

    // ---- single 16-lane shuffle reduce (hoisted out of the b loop) ----
    #pragma unroll
    for (int off = 1; off < 16; off <<= 1)
        #pragma unroll
        for (int reg = 0; reg < 4; ++reg)
            outAcc[reg] += __shfl_xor(outAcc[reg], off);

    // ---- write partial[z][bg][a]: lanes m==0 hold a = wv*16 + quad*4 + reg ----
    if (m == 0) {
        float4 st;
        st.x = outAcc[0]; st.y = outAcc[1]; st.z = outAcc[2]; st.w = outAcc[3];
        *reinterpret_cast<float4*>(partial + ((size_t)(z * 16 + bg)) * 64 + wv * 16 + quad * 4) = st;
    }

    // ---- fused finalize: canonical last-block-done sequence ----
    __threadfence();      // release: each thread's partial stores visible
    __syncthreads();      // ALL waves' stores + fences complete before signal
    if (tid == 0)
        lastFlag = (atomicAdd(&counters[z], 1) == 15);
    __syncthreads();
    if (lastFlag) {
        __threadfence();  // acquire: other blocks' partials
        if (tid < 64) {
            const int a = tid;
            const float mk = mask[z * 64 + a];
            float s = mk;
            #pragma unroll
            for (int off = 32; off > 0; off >>= 1) s += __shfl_xor(s, off);
            const float inv = rsqrtf(s);
            float acc2 = 0.f;
            #pragma unroll
            for (int bg2 = 0; bg2 < 16; ++bg2)
                acc2 += partial[((size_t)(z * 16 + bg2)) * 64 + a];
            out[z * 64 + a] = sp_f(acc2 * inv) * mk;
        }
    }
}

extern "C" void kernel_launch(void* const* d_in, const int* in_sizes, int n_in,
                              void* d_out, int out_size, void* d_ws, size_t ws_size,
                              hipStream_t stream) {
    const float* rep  = (const float*)d_in[0];
    const float* geom = (const float*)d_in[1];
    const float* mask = (const float*)d_in[2];
    const float* W1   = (const float*)d_in[3];
    const float* W2   = (const float*)d_in[4];
    const float* W3   = (const float*)d_in[5];
    float* out = (float*)d_out;

    _Float16* w2f = (_Float16*)d_ws;                          // 32768 B
    float* partial = (float*)((char*)d_ws + 32768);           // 64*16*64*4 = 262144 B
    int* counters = (int*)((char*)d_ws + 32768 + 262144);     // 256 B

    w2half<<<16, 256, 0, stream>>>(W2, w2f, counters);
    pair4<<<dim3(16, 64), 256, 0, stream>>>(rep, geom, W1, W3, w2f, mask,
                                            partial, counters, out);
}

// Round 8
// 134.586 us; speedup vs baseline: 1.6113x; 1.5417x over previous
//
#include <hip/hip_runtime.h>
#include <math.h>

// B=64, A=64, MULS=((64,0),(32,1),(16,2)) -> DIM_IN=240, NB=32, H=128, MOUT=112
#define H_ 128
#define NB_ 32

#define INV_STEP 3.1f
#define HALF_PI 1.57079632679489662f
#define INV_SQRT_NB 0.17677669529663689f
#define INV_SQRT_H 0.08838834764831845f
#define NORM0 0.125f
#define NORM1 0.10206207261596575f
#define NORM2 0.11180339887498948f
#define S3 1.7320508075688772f
#define S5 2.23606797749979f
#define S15 3.872983346207417f
#define LN2 0.6931471805599453f

typedef __attribute__((ext_vector_type(8))) _Float16 half8;
typedef __attribute__((ext_vector_type(4))) float f32x4;

__device__ __forceinline__ float ssp_f(float x) {
    float t = 5.0f * x;
    float s = fmaxf(t, 0.0f) + __logf(1.0f + __expf(-fabsf(t)));
    return (s - LN2) * 0.2f;
}
__device__ __forceinline__ float sp_f(float x) {
    float t = 5.0f * x;
    float s = fmaxf(t, 0.0f) + __logf(1.0f + __expf(-fabsf(t)));
    return s * 0.2f;
}

// ---------------------------------------------------------------------------
// w2half: W2 (fp32 row-major) -> fp16 MFMA-B-fragment order in ws.
// pos = ((kt*8+nt)*64 + lane)*8 + j ; k = kt*32+(lane>>4)*8+j ; n = nt*16+(lane&15)
// ---------------------------------------------------------------------------
__global__ void w2half(const float* __restrict__ W2, _Float16* __restrict__ w2f) {
    const int e0 = (blockIdx.x * 256 + threadIdx.x) * 4;
    #pragma unroll
    for (int t = 0; t < 4; ++t) {
        const int pos = e0 + t;
        const int j = pos & 7, lane = (pos >> 3) & 63, fn = pos >> 9;
        const int kt = fn >> 3, nt = fn & 7;
        const int k = kt * 32 + (lane >> 4) * 8 + j;
        const int n = nt * 16 + (lane & 15);
        w2f[pos] = (_Float16)W2[k * 128 + n];
    }
}

// ---------------------------------------------------------------------------
// pair4: Round-8 = the PROVEN R0 structure (82 µs pair4 / 139.7 total),
// re-anchored after 4 regressed exploration rounds, with only independently
// verified deltas:
//   - grid 512 (8 bg x 64 z), 8 b/block, 4 passes x 2-b pairs,
//     __launch_bounds__(256,2): 128 arch regs, 0 spill (R0-measured).
//   - fp16 per-wave sH2t transpose (R4-verified): LDS 72->~50 KB, bank
//     conflicts halved (2.69M -> 1.25M measured). Occupancy unchanged
//     (reg-bound 2 blocks/CU either way).
//   - 16-lane shuffle reduce hoisted out of the b loop (R7-verified):
//     saves ~192 VALU insts/thread.
//   - NO fused finalize / NO __threadfence: R6/R7 isolated the fused
//     epilogue as a ~60-70 µs makespan cost (agent-scope fence = L2
//     writeback/invalidate per block; re-fetches hit L3 so FETCH_SIZE
//     stayed flat while duration doubled). Separate tiny finalize kernel.
//   - sRep staged in LDS for V-compute (part of the proven-82 config).
// ---------------------------------------------------------------------------
__global__ __launch_bounds__(256, 2)
void pair4(const float* __restrict__ rep, const float* __restrict__ geom,
           const float* __restrict__ W1, const float* __restrict__ W3,
           const _Float16* __restrict__ w2f, float* __restrict__ partial) {
    const int bg = blockIdx.x;           // b in [8bg, 8bg+8)
    const int z  = blockIdx.y;
    const int tid = threadIdx.x;
    const int wv = tid >> 6, lane = tid & 63;
    const int m = lane & 15, quad = lane >> 4;

    __shared__ __align__(16) _Float16 sVf[16384];      // 32768 B  [b<8][kt][lane][j]
    __shared__ __align__(16) _Float16 sH2t[4][16][40]; // 5120 B   per-wave [a][h2local+pad]
    __shared__ __align__(16) float sRep[1920];         // 7680 B   8 rep rows
    __shared__ float sYw[4][2][16][8];                 // 4096 B
    __shared__ float sPosA[192];                       // 768 B
    __shared__ float sPosB[24];                        // 96 B
    // total ~50.5 KB; reg-bound 2 blocks/CU (101 KB < 160 KB)

    // ---- startup: stage geom + rep ----
    if (tid < 192) sPosA[tid] = geom[z * 192 + tid];
    else if (tid < 216) sPosB[tid - 192] = geom[((size_t)z * 64 + bg * 8) * 3 + (tid - 192)];
    {
        const float4* src = reinterpret_cast<const float4*>(rep + ((size_t)z * 64 + bg * 8) * 240);
        float4* dst = reinterpret_cast<float4*>(sRep);
        for (int i = tid; i < 480; i += 256) dst[i] = src[i];
    }
    __syncthreads();

    // ---- V compute: 1024 slots (b,h); emit fp16 B-frags (16 n's incl. zeros) ----
    #pragma unroll
    for (int i = 0; i < 4; ++i) {
        const int s = tid + i * 256;
        const int b = s >> 7, h = s & 127;
        const float* w3r = W3 + (size_t)h * 112;
        const float* rr = sRep + b * 240;
        float a0 = 0.f, a1 = 0.f, a2 = 0.f, a3 = 0.f, a4 = 0.f,
              a5 = 0.f, a6 = 0.f, a7 = 0.f, a8 = 0.f;
        #pragma unroll 4
        for (int m4 = 0; m4 < 16; ++m4) {            // l=0
            float4 w = *reinterpret_cast<const float4*>(w3r + m4 * 4);
            const float* wp = reinterpret_cast<const float*>(&w);
            #pragma unroll
            for (int c = 0; c < 4; ++c) a0 = fmaf(wp[c], rr[m4 * 4 + c], a0);
        }
        #pragma unroll 2
        for (int u4 = 0; u4 < 8; ++u4) {             // l=1
            float4 w = *reinterpret_cast<const float4*>(w3r + 64 + u4 * 4);
            const float* wp = reinterpret_cast<const float*>(&w);
            #pragma unroll
            for (int c = 0; c < 4; ++c) {
                int u = u4 * 4 + c;
                a1 = fmaf(wp[c], rr[64 + 3 * u + 0], a1);
                a2 = fmaf(wp[c], rr[64 + 3 * u + 1], a2);
                a3 = fmaf(wp[c], rr[64 + 3 * u + 2], a3);
            }
        }
        #pragma unroll 2
        for (int u4 = 0; u4 < 4; ++u4) {             // l=2
            float4 w = *reinterpret_cast<const float4*>(w3r + 96 + u4 * 4);
            const float* wp = reinterpret_cast<const float*>(&w);
            #pragma unroll
            for (int c = 0; c < 4; ++c) {
                int u = u4 * 4 + c;
                a4 = fmaf(wp[c], rr[160 + 5 * u + 0], a4);
                a5 = fmaf(wp[c], rr[160 + 5 * u + 1], a5);
                a6 = fmaf(wp[c], rr[160 + 5 * u + 2], a6);
                a7 = fmaf(wp[c], rr[160 + 5 * u + 3], a7);
                a8 = fmaf(wp[c], rr[160 + 5 * u + 4], a8);
            }
        }
        const float n0 = NORM0 * INV_SQRT_H, n1 = NORM1 * INV_SQRT_H, n2 = NORM2 * INV_SQRT_H;
        float vals[9];
        vals[0] = a0 * n0;
        vals[1] = a1 * n1; vals[2] = a2 * n1; vals[3] = a3 * n1;
        vals[4] = a4 * n2; vals[5] = a5 * n2; vals[6] = a6 * n2;
        vals[7] = a7 * n2; vals[8] = a8 * n2;
        // h = kt*32 + qd*8 + j ; frag pos = (b*4+kt)*512 + (qd*16+n)*8 + j
        const int kt = h >> 5, qd = (h >> 3) & 3, j = h & 7;
        _Float16* base = sVf + (b * 4 + kt) * 512 + qd * 128 + j;
        #pragma unroll
        for (int n = 0; n < 16; ++n)
            base[n * 8] = (n < 9) ? (_Float16)vals[n] : (_Float16)0.0f;
    }
    __syncthreads();   // sVf + sPos* ready

    // ---- main loop: 4 passes x 2-b pairs (R0's proven structure) ----
    const int aLoc = wv * 16 + m;
    const float ax = sPosA[aLoc * 3 + 0];
    const float ay = sPosA[aLoc * 3 + 1];
    const float az = sPosA[aLoc * 3 + 2];
    float outAcc[4] = {0.f, 0.f, 0.f, 0.f};

    for (int pass = 0; pass < 4; ++pass) {
        const float* w1p0[2];
        const float* w1p1[2];
        float c0v[2], c1v[2];

        #pragma unroll
        for (int p = 0; p < 2; ++p) {
            const int bl = pass * 2 + p;
            const float bx = sPosB[bl * 3 + 0];
            const float by = sPosB[bl * 3 + 1];
            const float bz = sPosB[bl * 3 + 2];
            const float dx = ax - bx, dy = ay - by, dz = az - bz;
            const float r2 = dx * dx + dy * dy + dz * dz;
            const float r = sqrtf(fmaxf(r2, 1e-12f));
            const float nzf = (r2 > 1e-10f) ? 1.0f : 0.0f;
            const float ir = 1.0f / r;
            const float x = dx * ir, y = dy * ir, zz = dz * ir;
            if (quad == 0) {
                float4 g0, g1;
                g0.x = S3 * x * nzf; g0.y = S3 * y * nzf; g0.z = S3 * zz * nzf;
                g0.w = S15 * x * y * nzf;
                g1.x = S15 * y * zz * nzf;
                g1.y = 0.5f * S5 * (3.0f * zz * zz - 1.0f) * nzf;
                g1.z = S15 * x * zz * nzf;
                g1.w = 0.5f * S15 * (x * x - y * y) * nzf;
                *reinterpret_cast<float4*>(&sYw[wv][p][m][0]) = g0;
                *reinterpret_cast<float4*>(&sYw[wv][p][m][4]) = g1;
            }
            const float u = r * INV_STEP;
            int i0 = (int)floorf(u);
            const float d0 = u - (float)i0;
            float c0 = (i0 >= 0 && i0 < NB_) ? __cosf(HALF_PI * d0) : 0.f;
            const int i1 = i0 + 1;
            const float d1 = d0 - 1.0f;
            float c1 = (i1 >= 0 && i1 < NB_ && d1 > -1.0f) ? __cosf(HALF_PI * d1) : 0.f;
            const int i0c = min(max(i0, 0), NB_ - 1);
            const int i1c = min(max(i1, 0), NB_ - 1);
            w1p0[p] = W1 + i0c * H_;
            w1p1[p] = W1 + i1c * H_;
            c0v[p] = c0 * INV_SQRT_NB;
            c1v[p] = c1 * INV_SQRT_NB;
        }

        f32x4 acc[2][8];
        #pragma unroll
        for (int p = 0; p < 2; ++p)
            #pragma unroll
            for (int nt = 0; nt < 8; ++nt) {
                acc[p][nt][0] = 0.f; acc[p][nt][1] = 0.f;
                acc[p][nt][2] = 0.f; acc[p][nt][3] = 0.f;
            }

        // ---- layer1 (fp16 A-frag regs) + layer2 fp16 MFMA ----
        #pragma unroll
        for (int kt = 0; kt < 4; ++kt) {
            const int koff = kt * 32 + quad * 8;
            half8 ah[2];
            #pragma unroll
            for (int p = 0; p < 2; ++p) {
                float4 wa0 = *reinterpret_cast<const float4*>(w1p0[p] + koff);
                float4 wa1 = *reinterpret_cast<const float4*>(w1p0[p] + koff + 4);
                float4 wb0 = *reinterpret_cast<const float4*>(w1p1[p] + koff);
                float4 wb1 = *reinterpret_cast<const float4*>(w1p1[p] + koff + 4);
                const float* a0p = reinterpret_cast<const float*>(&wa0);
                const float* a1p = reinterpret_cast<const float*>(&wa1);
                const float* b0p = reinterpret_cast<const float*>(&wb0);
                const float* b1p = reinterpret_cast<const float*>(&wb1);
                #pragma unroll
                for (int j = 0; j < 8; ++j) {
                    float w0 = (j < 4) ? a0p[j] : a1p[j - 4];
                    float w1v = (j < 4) ? b0p[j] : b1p[j - 4];
                    ah[p][j] = (_Float16)ssp_f(fmaf(c0v[p], w0, c1v[p] * w1v));
                }
            }
            const _Float16* bhp = w2f + (size_t)(kt * 8) * 512 + (size_t)lane * 8;
            #pragma unroll
            for (int nt = 0; nt < 8; ++nt) {
                half8 bh = *reinterpret_cast<const half8*>(bhp + nt * 512);
                acc[0][nt] = __builtin_amdgcn_mfma_f32_16x16x32_f16(ah[0], bh, acc[0][nt], 0, 0, 0);
                acc[1][nt] = __builtin_amdgcn_mfma_f32_16x16x32_f16(ah[1], bh, acc[1][nt], 0, 0, 0);
            }
        }

        // ---- per-b epilogue ----
        #pragma unroll
        for (int p = 0; p < 2; ++p) {
            const int bl = pass * 2 + p;

            // ssp + per-kt fp16 transpose through wave-private LDS, combine
            f32x4 T0 = {0.f, 0.f, 0.f, 0.f};
            f32x4 T1 = {0.f, 0.f, 0.f, 0.f};
            #pragma unroll
            for (int kt = 0; kt < 4; ++kt) {
                #pragma unroll
                for (int ntl = 0; ntl < 2; ++ntl)
                    #pragma unroll
                    for (int reg = 0; reg < 4; ++reg)
                        sH2t[wv][quad * 4 + reg][ntl * 16 + m] =
                            (_Float16)ssp_f(acc[p][kt * 2 + ntl][reg] * INV_SQRT_H);
                half8 ah2 = *reinterpret_cast<const half8*>(&sH2t[wv][m][quad * 8]);
                half8 bv = *reinterpret_cast<const half8*>(sVf + (bl * 4 + kt) * 512 + lane * 8);
                if (kt & 1) T1 = __builtin_amdgcn_mfma_f32_16x16x32_f16(ah2, bv, T1, 0, 0, 0);
                else        T0 = __builtin_amdgcn_mfma_f32_16x16x32_f16(ah2, bv, T0, 0, 0, 0);
            }

            // G-weight; reduce DEFERRED: accumulate unreduced lane-partials
            const int comp = (m >= 1 && m <= 8) ? (m - 1) : 0;
            #pragma unroll
            for (int reg = 0; reg < 4; ++reg) {
                const int row = quad * 4 + reg;
                const float Tv = T0[reg] + T1[reg];
                const float yv = sYw[wv][p][row][comp];
                const float g = (m == 0) ? 1.0f : ((m <= 8) ? yv : 0.0f);
                outAcc[reg] = fmaf(Tv, g, outAcc[reg]);
            }
        }
    }

    // ---- single 16-lane shuffle reduce (hoisted out of the b loop) ----
    #pragma unroll
    for (int off = 1; off < 16; off <<= 1)
        #pragma unroll
        for (int reg = 0; reg < 4; ++reg)
            outAcc[reg] += __shfl_xor(outAcc[reg], off);

    // ---- write partial[z][bg][a]: lanes m==0 hold a = wv*16 + quad*4 + reg ----
    if (m == 0) {
        float4 st;
        st.x = outAcc[0]; st.y = outAcc[1]; st.z = outAcc[2]; st.w = outAcc[3];
        *reinterpret_cast<float4*>(partial + ((size_t)(z * 8 + bg)) * 64 + wv * 16 + quad * 4) = st;
    }
}

// ---------------------------------------------------------------------------
// finalize: out[z,a] = sp( (sum_bg partial) / sqrt(n_atoms) ) * mask
// ---------------------------------------------------------------------------
__global__ __launch_bounds__(64, 8)
void finalize(const float* __restrict__ partial, const float* __restrict__ mask,
              float* __restrict__ out) {
    const int z = blockIdx.x, a = threadIdx.x;
    const float mk = mask[z * 64 + a];
    float s = mk;
    #pragma unroll
    for (int off = 32; off > 0; off >>= 1) s += __shfl_xor(s, off);
    const float inv = rsqrtf(s);
    float acc = 0.f;
    #pragma unroll
    for (int bg = 0; bg < 8; ++bg)
        acc += partial[((size_t)(z * 8 + bg)) * 64 + a];
    out[z * 64 + a] = sp_f(acc * inv) * mk;
}

extern "C" void kernel_launch(void* const* d_in, const int* in_sizes, int n_in,
                              void* d_out, int out_size, void* d_ws, size_t ws_size,
                              hipStream_t stream) {
    const float* rep  = (const float*)d_in[0];
    const float* geom = (const float*)d_in[1];
    const float* mask = (const float*)d_in[2];
    const float* W1   = (const float*)d_in[3];
    const float* W2   = (const float*)d_in[4];
    const float* W3   = (const float*)d_in[5];
    float* out = (float*)d_out;

    _Float16* w2f = (_Float16*)d_ws;                       // 32768 B
    float* partial = (float*)((char*)d_ws + 32768);        // 512*64*4 = 131072 B

    w2half<<<16, 256, 0, stream>>>(W2, w2f);
    pair4<<<dim3(8, 64), 256, 0, stream>>>(rep, geom, W1, W3, w2f, partial);
    finalize<<<64, 64, 0, stream>>>(partial, mask, out);
}

// Round 9
// 133.113 us; speedup vs baseline: 1.6292x; 1.0111x over previous
//
#include <hip/hip_runtime.h>
#include <math.h>

// B=64, A=64, MULS=((64,0),(32,1),(16,2)) -> DIM_IN=240, NB=32, H=128, MOUT=112
#define H_ 128
#define NB_ 32

#define INV_STEP 3.1f
#define HALF_PI 1.57079632679489662f
#define INV_SQRT_NB 0.17677669529663689f
#define INV_SQRT_H 0.08838834764831845f
#define NORM0 0.125f
#define NORM1 0.10206207261596575f
#define NORM2 0.11180339887498948f
#define S3 1.7320508075688772f
#define S5 2.23606797749979f
#define S15 3.872983346207417f
#define LN2 0.6931471805599453f

typedef __attribute__((ext_vector_type(8))) _Float16 half8;
typedef __attribute__((ext_vector_type(4))) float f32x4;

__device__ __forceinline__ float ssp_f(float x) {
    float t = 5.0f * x;
    float s = fmaxf(t, 0.0f) + __logf(1.0f + __expf(-fabsf(t)));
    return (s - LN2) * 0.2f;
}
__device__ __forceinline__ float sp_f(float x) {
    float t = 5.0f * x;
    float s = fmaxf(t, 0.0f) + __logf(1.0f + __expf(-fabsf(t)));
    return s * 0.2f;
}

// ---------------------------------------------------------------------------
// pair4: Round-9 = R8 (verified 77 µs pair4 / 134.6 total) with w2half
// FOLDED IN: each block converts W2 fp32 -> fp16 MFMA-B fragments into LDS
// at startup (launch accounting over R0-R8: ~11 µs/launch of gap; w2half's
// work is microseconds). LDS 50.7 -> 75.6 KB, still 2 blocks/CU (151<160K)
// by aliasing the dead sRep staging buffer into the sW2f region (sRep dead
// after V-compute; barrier separates phases). Main-loop B-frag loads become
// lane-contiguous ds_read_b128 (conflict-free), freeing vmem for W1 gathers.
// Carried from R8 (all verified): grid 512, 4 passes x 2-b pairs, (256,2)
// 128-reg/0-spill body, fp16 sH2t transpose, hoisted reduce, separate tiny
// finalize kernel (NO threadfence — R6/R7 isolated agent-scope fence as a
// ~60 µs makespan cost).
// ---------------------------------------------------------------------------
__global__ __launch_bounds__(256, 2)
void pair4(const float* __restrict__ rep, const float* __restrict__ geom,
           const float* __restrict__ W1, const float* __restrict__ W2,
           const float* __restrict__ W3, float* __restrict__ partial) {
    const int bg = blockIdx.x;           // b in [8bg, 8bg+8)
    const int z  = blockIdx.y;
    const int tid = threadIdx.x;
    const int wv = tid >> 6, lane = tid & 63;
    const int m = lane & 15, quad = lane >> 4;

    __shared__ __align__(16) _Float16 sVf[16384];      // 32768 B  [b<8][kt][lane][j]
    __shared__ __align__(16) _Float16 sW2f[16384];     // 32768 B  W2 B-frags (aliases sRep @startup)
    __shared__ __align__(16) _Float16 sH2t[4][16][40]; // 5120 B   per-wave [a][h2local+pad]
    __shared__ float sYw[4][2][16][8];                 // 4096 B
    __shared__ float sPosA[192];                       // 768 B
    __shared__ float sPosB[24];                        // 96 B
    // total ~75.6 KB -> 2 blocks/CU (151 KB < 160 KB); reg-bound anyway

    float* sRep = reinterpret_cast<float*>(sW2f);      // 1920 floats, dead before W2 staging

    // ---- startup: stage geom + rep ----
    if (tid < 192) sPosA[tid] = geom[z * 192 + tid];
    else if (tid < 216) sPosB[tid - 192] = geom[((size_t)z * 64 + bg * 8) * 3 + (tid - 192)];
    {
        const float4* src = reinterpret_cast<const float4*>(rep + ((size_t)z * 64 + bg * 8) * 240);
        float4* dst = reinterpret_cast<float4*>(sRep);
        for (int i = tid; i < 480; i += 256) dst[i] = src[i];
    }
    __syncthreads();

    // ---- V compute: 1024 slots (b,h); emit fp16 B-frags (16 n's incl. zeros) ----
    #pragma unroll
    for (int i = 0; i < 4; ++i) {
        const int s = tid + i * 256;
        const int b = s >> 7, h = s & 127;
        const float* w3r = W3 + (size_t)h * 112;
        const float* rr = sRep + b * 240;
        float a0 = 0.f, a1 = 0.f, a2 = 0.f, a3 = 0.f, a4 = 0.f,
              a5 = 0.f, a6 = 0.f, a7 = 0.f, a8 = 0.f;
        #pragma unroll 4
        for (int m4 = 0; m4 < 16; ++m4) {            // l=0
            float4 w = *reinterpret_cast<const float4*>(w3r + m4 * 4);
            const float* wp = reinterpret_cast<const float*>(&w);
            #pragma unroll
            for (int c = 0; c < 4; ++c) a0 = fmaf(wp[c], rr[m4 * 4 + c], a0);
        }
        #pragma unroll 2
        for (int u4 = 0; u4 < 8; ++u4) {             // l=1
            float4 w = *reinterpret_cast<const float4*>(w3r + 64 + u4 * 4);
            const float* wp = reinterpret_cast<const float*>(&w);
            #pragma unroll
            for (int c = 0; c < 4; ++c) {
                int u = u4 * 4 + c;
                a1 = fmaf(wp[c], rr[64 + 3 * u + 0], a1);
                a2 = fmaf(wp[c], rr[64 + 3 * u + 1], a2);
                a3 = fmaf(wp[c], rr[64 + 3 * u + 2], a3);
            }
        }
        #pragma unroll 2
        for (int u4 = 0; u4 < 4; ++u4) {             // l=2
            float4 w = *reinterpret_cast<const float4*>(w3r + 96 + u4 * 4);
            const float* wp = reinterpret_cast<const float*>(&w);
            #pragma unroll
            for (int c = 0; c < 4; ++c) {
                int u = u4 * 4 + c;
                a4 = fmaf(wp[c], rr[160 + 5 * u + 0], a4);
                a5 = fmaf(wp[c], rr[160 + 5 * u + 1], a5);
                a6 = fmaf(wp[c], rr[160 + 5 * u + 2], a6);
                a7 = fmaf(wp[c], rr[160 + 5 * u + 3], a7);
                a8 = fmaf(wp[c], rr[160 + 5 * u + 4], a8);
            }
        }
        const float n0 = NORM0 * INV_SQRT_H, n1 = NORM1 * INV_SQRT_H, n2 = NORM2 * INV_SQRT_H;
        float vals[9];
        vals[0] = a0 * n0;
        vals[1] = a1 * n1; vals[2] = a2 * n1; vals[3] = a3 * n1;
        vals[4] = a4 * n2; vals[5] = a5 * n2; vals[6] = a6 * n2;
        vals[7] = a7 * n2; vals[8] = a8 * n2;
        // h = kt*32 + qd*8 + j ; frag pos = (b*4+kt)*512 + (qd*16+n)*8 + j
        const int kt = h >> 5, qd = (h >> 3) & 3, j = h & 7;
        _Float16* base = sVf + (b * 4 + kt) * 512 + qd * 128 + j;
        #pragma unroll
        for (int n = 0; n < 16; ++n)
            base[n * 8] = (n < 9) ? (_Float16)vals[n] : (_Float16)0.0f;
    }
    __syncthreads();   // V-compute done reading sRep; sW2f region reusable

    // ---- W2 -> fp16 B-frags in LDS (was the separate w2half kernel) ----
    // thread handles row k = tid>>1, n-half nh = tid&1: 16 coalesced float4
    // reads, 64 b16 scatter writes. frag pos = ((kt*8+nt)*64+lane)*8+j with
    // k = kt*32+(lane>>4)*8+j, n = nt*16+(lane&15)  (same mapping as w2half).
    {
        const int k = tid >> 1, nh = tid & 1;
        const int kt = k >> 5, j = k & 7, lh = (k >> 3) & 3;
        const float4* src = reinterpret_cast<const float4*>(W2 + k * 128 + nh * 64);
        #pragma unroll
        for (int q = 0; q < 16; ++q) {
            float4 w = src[q];
            const float* wp = reinterpret_cast<const float*>(&w);
            #pragma unroll
            for (int c = 0; c < 4; ++c) {
                const int n = nh * 64 + q * 4 + c;
                const int nt = n >> 4, ln = lh * 16 + (n & 15);
                sW2f[((kt * 8 + nt) * 64 + ln) * 8 + j] = (_Float16)wp[c];
            }
        }
    }
    __syncthreads();   // sVf + sW2f + sPos* ready

    // ---- main loop: 4 passes x 2-b pairs (R0/R8's proven structure) ----
    const int aLoc = wv * 16 + m;
    const float ax = sPosA[aLoc * 3 + 0];
    const float ay = sPosA[aLoc * 3 + 1];
    const float az = sPosA[aLoc * 3 + 2];
    float outAcc[4] = {0.f, 0.f, 0.f, 0.f};

    for (int pass = 0; pass < 4; ++pass) {
        const float* w1p0[2];
        const float* w1p1[2];
        float c0v[2], c1v[2];

        #pragma unroll
        for (int p = 0; p < 2; ++p) {
            const int bl = pass * 2 + p;
            const float bx = sPosB[bl * 3 + 0];
            const float by = sPosB[bl * 3 + 1];
            const float bz = sPosB[bl * 3 + 2];
            const float dx = ax - bx, dy = ay - by, dz = az - bz;
            const float r2 = dx * dx + dy * dy + dz * dz;
            const float r = sqrtf(fmaxf(r2, 1e-12f));
            const float nzf = (r2 > 1e-10f) ? 1.0f : 0.0f;
            const float ir = 1.0f / r;
            const float x = dx * ir, y = dy * ir, zz = dz * ir;
            if (quad == 0) {
                float4 g0, g1;
                g0.x = S3 * x * nzf; g0.y = S3 * y * nzf; g0.z = S3 * zz * nzf;
                g0.w = S15 * x * y * nzf;
                g1.x = S15 * y * zz * nzf;
                g1.y = 0.5f * S5 * (3.0f * zz * zz - 1.0f) * nzf;
                g1.z = S15 * x * zz * nzf;
                g1.w = 0.5f * S15 * (x * x - y * y) * nzf;
                *reinterpret_cast<float4*>(&sYw[wv][p][m][0]) = g0;
                *reinterpret_cast<float4*>(&sYw[wv][p][m][4]) = g1;
            }
            const float u = r * INV_STEP;
            int i0 = (int)floorf(u);
            const float d0 = u - (float)i0;
            float c0 = (i0 >= 0 && i0 < NB_) ? __cosf(HALF_PI * d0) : 0.f;
            const int i1 = i0 + 1;
            const float d1 = d0 - 1.0f;
            float c1 = (i1 >= 0 && i1 < NB_ && d1 > -1.0f) ? __cosf(HALF_PI * d1) : 0.f;
            const int i0c = min(max(i0, 0), NB_ - 1);
            const int i1c = min(max(i1, 0), NB_ - 1);
            w1p0[p] = W1 + i0c * H_;
            w1p1[p] = W1 + i1c * H_;
            c0v[p] = c0 * INV_SQRT_NB;
            c1v[p] = c1 * INV_SQRT_NB;
        }

        f32x4 acc[2][8];
        #pragma unroll
        for (int p = 0; p < 2; ++p)
            #pragma unroll
            for (int nt = 0; nt < 8; ++nt) {
                acc[p][nt][0] = 0.f; acc[p][nt][1] = 0.f;
                acc[p][nt][2] = 0.f; acc[p][nt][3] = 0.f;
            }

        // ---- layer1 (fp16 A-frag regs) + layer2 fp16 MFMA (B-frags via LDS) ----
        #pragma unroll
        for (int kt = 0; kt < 4; ++kt) {
            const int koff = kt * 32 + quad * 8;
            half8 ah[2];
            #pragma unroll
            for (int p = 0; p < 2; ++p) {
                float4 wa0 = *reinterpret_cast<const float4*>(w1p0[p] + koff);
                float4 wa1 = *reinterpret_cast<const float4*>(w1p0[p] + koff + 4);
                float4 wb0 = *reinterpret_cast<const float4*>(w1p1[p] + koff);
                float4 wb1 = *reinterpret_cast<const float4*>(w1p1[p] + koff + 4);
                const float* a0p = reinterpret_cast<const float*>(&wa0);
                const float* a1p = reinterpret_cast<const float*>(&wa1);
                const float* b0p = reinterpret_cast<const float*>(&wb0);
                const float* b1p = reinterpret_cast<const float*>(&wb1);
                #pragma unroll
                for (int j = 0; j < 8; ++j) {
                    float w0 = (j < 4) ? a0p[j] : a1p[j - 4];
                    float w1v = (j < 4) ? b0p[j] : b1p[j - 4];
                    ah[p][j] = (_Float16)ssp_f(fmaf(c0v[p], w0, c1v[p] * w1v));
                }
            }
            const _Float16* bhp = sW2f + (kt * 8) * 512 + lane * 8;
            #pragma unroll
            for (int nt = 0; nt < 8; ++nt) {
                half8 bh = *reinterpret_cast<const half8*>(bhp + nt * 512);
                acc[0][nt] = __builtin_amdgcn_mfma_f32_16x16x32_f16(ah[0], bh, acc[0][nt], 0, 0, 0);
                acc[1][nt] = __builtin_amdgcn_mfma_f32_16x16x32_f16(ah[1], bh, acc[1][nt], 0, 0, 0);
            }
        }

        // ---- per-b epilogue ----
        #pragma unroll
        for (int p = 0; p < 2; ++p) {
            const int bl = pass * 2 + p;

            // ssp + per-kt fp16 transpose through wave-private LDS, combine
            f32x4 T0 = {0.f, 0.f, 0.f, 0.f};
            f32x4 T1 = {0.f, 0.f, 0.f, 0.f};
            #pragma unroll
            for (int kt = 0; kt < 4; ++kt) {
                #pragma unroll
                for (int ntl = 0; ntl < 2; ++ntl)
                    #pragma unroll
                    for (int reg = 0; reg < 4; ++reg)
                        sH2t[wv][quad * 4 + reg][ntl * 16 + m] =
                            (_Float16)ssp_f(acc[p][kt * 2 + ntl][reg] * INV_SQRT_H);
                half8 ah2 = *reinterpret_cast<const half8*>(&sH2t[wv][m][quad * 8]);
                half8 bv = *reinterpret_cast<const half8*>(sVf + (bl * 4 + kt) * 512 + lane * 8);
                if (kt & 1) T1 = __builtin_amdgcn_mfma_f32_16x16x32_f16(ah2, bv, T1, 0, 0, 0);
                else        T0 = __builtin_amdgcn_mfma_f32_16x16x32_f16(ah2, bv, T0, 0, 0, 0);
            }

            // G-weight; reduce DEFERRED: accumulate unreduced lane-partials
            const int comp = (m >= 1 && m <= 8) ? (m - 1) : 0;
            #pragma unroll
            for (int reg = 0; reg < 4; ++reg) {
                const int row = quad * 4 + reg;
                const float Tv = T0[reg] + T1[reg];
                const float yv = sYw[wv][p][row][comp];
                const float g = (m == 0) ? 1.0f : ((m <= 8) ? yv : 0.0f);
                outAcc[reg] = fmaf(Tv, g, outAcc[reg]);
            }
        }
    }

    // ---- single 16-lane shuffle reduce (hoisted out of the b loop) ----
    #pragma unroll
    for (int off = 1; off < 16; off <<= 1)
        #pragma unroll
        for (int reg = 0; reg < 4; ++reg)
            outAcc[reg] += __shfl_xor(outAcc[reg], off);

    // ---- write partial[z][bg][a]: lanes m==0 hold a = wv*16 + quad*4 + reg ----
    if (m == 0) {
        float4 st;
        st.x = outAcc[0]; st.y = outAcc[1]; st.z = outAcc[2]; st.w = outAcc[3];
        *reinterpret_cast<float4*>(partial + ((size_t)(z * 8 + bg)) * 64 + wv * 16 + quad * 4) = st;
    }
}

// ---------------------------------------------------------------------------
// finalize: out[z,a] = sp( (sum_bg partial) / sqrt(n_atoms) ) * mask
// ---------------------------------------------------------------------------
__global__ __launch_bounds__(64, 8)
void finalize(const float* __restrict__ partial, const float* __restrict__ mask,
              float* __restrict__ out) {
    const int z = blockIdx.x, a = threadIdx.x;
    const float mk = mask[z * 64 + a];
    float s = mk;
    #pragma unroll
    for (int off = 32; off > 0; off >>= 1) s += __shfl_xor(s, off);
    const float inv = rsqrtf(s);
    float acc = 0.f;
    #pragma unroll
    for (int bg = 0; bg < 8; ++bg)
        acc += partial[((size_t)(z * 8 + bg)) * 64 + a];
    out[z * 64 + a] = sp_f(acc * inv) * mk;
}

extern "C" void kernel_launch(void* const* d_in, const int* in_sizes, int n_in,
                              void* d_out, int out_size, void* d_ws, size_t ws_size,
                              hipStream_t stream) {
    const float* rep  = (const float*)d_in[0];
    const float* geom = (const float*)d_in[1];
    const float* mask = (const float*)d_in[2];
    const float* W1   = (const float*)d_in[3];
    const float* W2   = (const float*)d_in[4];
    const float* W3   = (const float*)d_in[5];
    float* out = (float*)d_out;

    float* partial = (float*)d_ws;                         // 512*64*4 = 131072 B

    pair4<<<dim3(8, 64), 256, 0, stream>>>(rep, geom, W1, W2, W3, partial);
    finalize<<<64, 64, 0, stream>>>(partial, mask, out);
}